// Round 2
// baseline (161.515 us; speedup 1.0000x reference)
//
#include <hip/hip_runtime.h>
#include <hip/hip_bf16.h>
#include <float.h>

#define NTOK 8192   // B*G tokens
#define NCB  8192   // codebook entries
#define CDIM 256
#define KPTS 32
#define SQNT 24.0f  // i8 quantization scale
#define INV_CFOLD (SQNT * SQNT * 64.0f)   // d / CFOLD scale, CFOLD = 2/(S^2*128)

#define CG   4      // col-groups (argmin grid.x); pkeys slices = CG*2 = 8
#define NTPB 16     // 128-col tiles per argmin block

typedef __attribute__((ext_vector_type(8))) short short8;   // 8 bf16
typedef __attribute__((ext_vector_type(4))) float f32x4;
typedef __attribute__((ext_vector_type(4))) int i32x4;
typedef __attribute__((ext_vector_type(16))) int i32x16;
typedef unsigned int u32;
typedef unsigned long long u64;

__device__ __forceinline__ void gl_lds16(const void* g, void* l) {
  __builtin_amdgcn_global_load_lds(
      (const __attribute__((address_space(1))) u32*)(g),
      (__attribute__((address_space(3))) u32*)(l), 16, 0, 0);
}

__device__ __forceinline__ ushort bf16_rne(float x) {
  u32 u = __float_as_uint(x);
  return (ushort)((u + 0x7fffu + ((u >> 16) & 1u)) >> 16);
}

__device__ __forceinline__ int pack4i8(int a, int b, int c, int d) {
  return (a & 0xff) | ((b & 0xff) << 8) | ((c & 0xff) << 16) | ((d & 0xff) << 24);
}

// ---------------- fused prep + out zeroing ----------------
// i8 layouts emitted as 32-row x 32-k fragment blocks of 1 KB:
//   block (rt32, kc32) at byte ((rt32*8 + kc32)*1024);
//   within: lane = (k_half<<5)|row_in holds 16 consecutive k bytes
//   -> exactly the mfma_i32_32x32x32_i8 A/B fragment order.
__global__ __launch_bounds__(256) void prep_k(
    const float* __restrict__ pf, const float* __restrict__ cb,
    const float* __restrict__ w1, const float* __restrict__ w2,
    const float* __restrict__ w3,
    i32x4* __restrict__ pf1, i32x4* __restrict__ pf2,
    i32x4* __restrict__ cb1, i32x4* __restrict__ cb2,
    ushort* __restrict__ cb_bf, ushort* __restrict__ w1s,
    ushort* __restrict__ w2s, ushort* __restrict__ w3s,
    float* __restrict__ cnorm, float* __restrict__ out) {
  __shared__ float cred[4][16];
  if (blockIdx.x == 0 && threadIdx.x == 0) out[0] = 0.f;
  int gid = blockIdx.x * 4 + (threadIdx.x >> 6);
  int wv = threadIdx.x >> 6;
  int lane = threadIdx.x & 63, r16 = lane & 15, quad = lane >> 4;
  if (gid < 4096) {
    bool is_cb = gid >= 2048;
    int t = is_cb ? gid - 2048 : gid;
    int tile = t >> 2, kb = t & 3;   // kb64
    const float* src = is_cb ? cb : pf;
    int row = tile * 16 + r16;
    const float* sp = src + (size_t)row * CDIM + kb * 64 + quad * 16;
    float4 v0 = ((const float4*)sp)[0];
    float4 v1 = ((const float4*)sp)[1];
    float4 v2 = ((const float4*)sp)[2];
    float4 v3 = ((const float4*)sp)[3];
    float x[16] = {v0.x, v0.y, v0.z, v0.w, v1.x, v1.y, v1.z, v1.w,
                   v2.x, v2.y, v2.z, v2.w, v3.x, v3.y, v3.z, v3.w};
    int q1[16], q2[16];
    float s = 0.f;
#pragma unroll
    for (int e = 0; e < 16; e++) {
      float as = x[e] * SQNT;
      float a1 = rintf(as);
      a1 = fminf(fmaxf(a1, -127.f), 127.f);
      float a2 = rintf((as - a1) * 128.f);
      a2 = fminf(fmaxf(a2, -127.f), 127.f);
      q1[e] = (int)a1;
      q2[e] = (int)a2;
      s += x[e] * x[e];
    }
    i32x4 p1 = {pack4i8(q1[0], q1[1], q1[2], q1[3]),
                pack4i8(q1[4], q1[5], q1[6], q1[7]),
                pack4i8(q1[8], q1[9], q1[10], q1[11]),
                pack4i8(q1[12], q1[13], q1[14], q1[15])};
    i32x4 p2 = {pack4i8(q2[0], q2[1], q2[2], q2[3]),
                pack4i8(q2[4], q2[5], q2[6], q2[7]),
                pack4i8(q2[8], q2[9], q2[10], q2[11]),
                pack4i8(q2[12], q2[13], q2[14], q2[15])};
    // 32x32 fragment-block layout (units of 16 B)
    int rt32 = tile >> 1;
    int row_in = ((tile & 1) << 4) | r16;
    int kc32 = (kb << 1) | (quad >> 1);
    int k_half = quad & 1;
    size_t o = (size_t)(rt32 * 8 + kc32) * 64 + k_half * 32 + row_in;
    (is_cb ? cb1 : pf1)[o] = p1;
    (is_cb ? cb2 : pf2)[o] = p2;
    if (is_cb) {
      int kb32 = 2 * kb + (quad >> 1);
      int slot0 = ((2 * quad) & 3) * 16 + r16;
      int slot1 = ((2 * quad + 1) & 3) * 16 + r16;
      size_t bo = ((size_t)tile * 8 + kb32) * 512;
      short8 vh0 = {(short)bf16_rne(x[0]), (short)bf16_rne(x[1]),
                    (short)bf16_rne(x[2]), (short)bf16_rne(x[3]),
                    (short)bf16_rne(x[4]), (short)bf16_rne(x[5]),
                    (short)bf16_rne(x[6]), (short)bf16_rne(x[7])};
      short8 vh1 = {(short)bf16_rne(x[8]), (short)bf16_rne(x[9]),
                    (short)bf16_rne(x[10]), (short)bf16_rne(x[11]),
                    (short)bf16_rne(x[12]), (short)bf16_rne(x[13]),
                    (short)bf16_rne(x[14]), (short)bf16_rne(x[15])};
      *(short8*)(cb_bf + bo + (size_t)slot0 * 8) = vh0;
      *(short8*)(cb_bf + bo + (size_t)slot1 * 8) = vh1;
      s += __shfl_xor(s, 16, 64);
      s += __shfl_xor(s, 32, 64);
      if (quad == 0) cred[wv][r16] = s;
      __syncthreads();
      if (threadIdx.x < 16) {
        int ctile = blockIdx.x - 512;
        cnorm[ctile * 16 + threadIdx.x] =
            cred[0][threadIdx.x] + cred[1][threadIdx.x] +
            cred[2][threadIdx.x] + cred[3][threadIdx.x];
      }
    }
  } else if (gid < 4656) {
    int t = gid - 4096;
    const float* src;
    ushort* dst;
    int KB;
    if (t < 256)      { src = w1; dst = w1s; KB = 8; }
    else if (t < 512) { src = w2; dst = w2s; KB = 16; t -= 256; }
    else              { src = w3; dst = w3s; KB = 8;  t -= 512; }
    int tile = t / KB, kb = t - tile * KB, K = KB * 32;
    int row = tile * 16 + r16;
    const float* sp = src + (size_t)row * K + kb * 32 + quad * 8;
    float4 a = ((const float4*)sp)[0];
    float4 b = ((const float4*)sp)[1];
    short8 vh = {(short)bf16_rne(a.x), (short)bf16_rne(a.y),
                 (short)bf16_rne(a.z), (short)bf16_rne(a.w),
                 (short)bf16_rne(b.x), (short)bf16_rne(b.y),
                 (short)bf16_rne(b.z), (short)bf16_rne(b.w)};
    *(short8*)(dst + ((size_t)tile * KB + kb) * 512 + lane * 8) = vh;
  }
}

// ---- argmin helpers (all static indexing after inlining) ----
__device__ __forceinline__ void stage_b(const char* __restrict__ B1g,
                                        const char* __restrict__ B2g,
                                        size_t ctb, int kh, char* dst,
                                        int wv, int lane) {
  // 32 chunks of 1 KB: lv(2) x ct(4) x kc(4); 8 per wave
#pragma unroll
  for (int u = 0; u < 8; ++u) {
    int c = wv * 8 + u;
    int lv = c >> 4, ct = (c >> 2) & 3, kc = (c & 3) + kh * 4;
    const char* src = (lv ? B2g : B1g) +
                      ((ctb + ct) * 8 + kc) * 1024 + (size_t)lane * 16;
    gl_lds16(src, dst + c * 1024);
  }
}

template <int KH>
__device__ __forceinline__ void phase_mfma(const char* bcur, int wc, int lane,
                                           const i32x4* a1, const i32x4* a2,
                                           i32x16* am, i32x16* ac) {
#pragma unroll
  for (int kk = 0; kk < 4; ++kk) {
#pragma unroll
    for (int j = 0; j < 2; ++j) {
      int ct = wc * 2 + j;
      i32x4 b1 = *(const i32x4*)(bcur + (ct * 4 + kk) * 1024 + lane * 16);
      i32x4 b2 = *(const i32x4*)(bcur + (16 + ct * 4 + kk) * 1024 + lane * 16);
      am[j] = __builtin_amdgcn_mfma_i32_32x32x32_i8(a1[KH * 4 + kk], b1, am[j], 0, 0, 0);
      ac[j] = __builtin_amdgcn_mfma_i32_32x32x32_i8(a1[KH * 4 + kk], b2, ac[j], 0, 0, 0);
      ac[j] = __builtin_amdgcn_mfma_i32_32x32x32_i8(a2[KH * 4 + kk], b1, ac[j], 0, 0, 0);
    }
  }
}

// -------- i8 32x32x32 MFMA distance GEMM + argmin --------
// A (64 rows x K=256, both levels) in REGISTERS (64 VGPR/wave).
// B double-buffered in LDS (2 x 32 KB), staged one phase ahead ->
// single barrier per 24-MFMA phase, staging latency hidden.
// Block: 256 thr = 4 waves (2 row-tiles x 2 col-halves), 64 rows x 2048 cols.
// Grid (CG=4, 128) = 512 blocks = exactly 2 blocks/CU residency.
__global__ __launch_bounds__(256, 2) void argmin_k(
    const char* __restrict__ A1g, const char* __restrict__ A2g,
    const char* __restrict__ B1g, const char* __restrict__ B2g,
    const float* __restrict__ cnorm, u64* __restrict__ pkeys) {
  extern __shared__ char lds[];
  char* buf0 = lds;
  char* buf1 = lds + 32768;
  int tid = threadIdx.x;
  int cg = blockIdx.x, mt = blockIdx.y;
  int wv = tid >> 6, lane = tid & 63;
  int rt = wv >> 1, wc = wv & 1;
  int l31 = lane & 31, lh = lane >> 5;

  // ---- A into regs: 2 levels x 8 k-chunks of 32 ----
  i32x4 a1[8], a2[8];
  {
    int rtg = mt * 2 + rt;
    const char* a1p = A1g + (size_t)rtg * 8192 + (size_t)lane * 16;
    const char* a2p = A2g + (size_t)rtg * 8192 + (size_t)lane * 16;
#pragma unroll
    for (int kc = 0; kc < 8; ++kc) {
      a1[kc] = *(const i32x4*)(a1p + kc * 1024);
      a2[kc] = *(const i32x4*)(a2p + kc * 1024);
    }
  }

  stage_b(B1g, B2g, (size_t)(cg * NTPB) * 4, 0, buf0, wv, lane);
  __syncthreads();

  int bvi[16], bii[16];
#pragma unroll
  for (int r = 0; r < 16; ++r) { bvi[r] = 0x7fffffff; bii[r] = 0x7fffffff; }

  i32x16 am[2], ac[2];

  for (int n = 0; n < NTPB; ++n) {
    size_t ctb = (size_t)(cg * NTPB + n) * 4;
    // ---- phase kh=0: stage (n,1)->buf1, compute buf0 ----
    stage_b(B1g, B2g, ctb, 1, buf1, wv, lane);
#pragma unroll
    for (int j = 0; j < 2; ++j)
#pragma unroll
      for (int r = 0; r < 16; ++r) { am[j][r] = 0; ac[j][r] = 0; }
    phase_mfma<0>(buf0, wc, lane, a1, a2, am, ac);
    __syncthreads();
    // ---- phase kh=1: stage (n+1,0)->buf0, compute buf1, fold ----
    if (n + 1 < NTPB) stage_b(B1g, B2g, ctb + 4, 0, buf0, wv, lane);
    phase_mfma<1>(buf1, wc, lane, a1, a2, am, ac);
    {
      int colbase = (cg * NTPB + n) * 128 + wc * 64;
#pragma unroll
      for (int j = 0; j < 2; ++j) {
        int col = colbase + j * 32 + l31;
        int cni = __float2int_rn(cnorm[col] * INV_CFOLD);
#pragma unroll
        for (int r = 0; r < 16; ++r) {
          int di = cni - (am[j][r] * 128 + ac[j][r]);
          if (di < bvi[r]) { bvi[r] = di; bii[r] = col; }
        }
      }
    }
    __syncthreads();
  }

  // reduce across the 32 lanes sharing each row set (lane&31 = col lanes)
#pragma unroll
  for (int m = 1; m < 32; m <<= 1) {
#pragma unroll
    for (int r = 0; r < 16; ++r) {
      int ov = __shfl_xor(bvi[r], m, 64);
      int oi = __shfl_xor(bii[r], m, 64);
      if (ov < bvi[r] || (ov == bvi[r] && oi < bii[r])) {
        bvi[r] = ov;
        bii[r] = oi;
      }
    }
  }
  if (l31 == 0) {
    int rowb = mt * 64 + rt * 32 + 4 * lh;
    size_t sbase = (size_t)(cg * 2 + wc) * NTOK;
#pragma unroll
    for (int r = 0; r < 16; ++r) {
      int row = rowb + (r & 3) + 8 * (r >> 2);
      u32 mk = (u32)(bvi[r] + (1 << 30));
      pkeys[sbase + row] = ((u64)mk << 32) | (u32)bii[r];
    }
  }
}

// -------- fused MLP: 16 tokens/block, 512 blocks x 512 thr ----
__global__ __launch_bounds__(512) void mlp_fused_k(
    const u64* __restrict__ pkeys, const ushort* __restrict__ cb_bf,
    const ushort* __restrict__ w1s, const float* __restrict__ b1,
    const ushort* __restrict__ w2s, const float* __restrict__ b2,
    const ushort* __restrict__ w3s, const float* __restrict__ b3,
    const float* __restrict__ neigh, float* __restrict__ out) {
  __shared__ ushort qs_h2[8 * 512];
  __shared__ ushort h1s[16 * 512];
  __shared__ float rec[16 * 96];
  __shared__ float gts[16 * 96];
  __shared__ int ids[16];
  __shared__ float wsum[8];

  int tid = threadIdx.x;
  int t0 = blockIdx.x * 16;
  int wv = tid >> 6, lane = tid & 63;
  int quad = lane >> 4, r16 = lane & 15;

  // 8 pkeys slices per token
  if (tid < 128) {
    int row_l = tid >> 3, sl = tid & 7;
    u64 best = pkeys[(size_t)sl * NTOK + t0 + row_l];
#pragma unroll
    for (int m = 1; m < 8; m <<= 1) {
      u64 o = __shfl_xor((unsigned long long)best, m, 64);
      if (o < best) best = o;
    }
    if (sl == 0) ids[row_l] = (int)(u32)best;
  }
  __syncthreads();

  {
    int kb = wv;
    int id = ids[r16];
    short8 v = *(const short8*)(cb_bf + ((size_t)(id >> 4) * 8 + kb) * 512 +
                                (size_t)((id & 15) + quad * 16) * 8);
    *(short8*)(qs_h2 + (size_t)kb * 512 + lane * 8) = v;
  }
  __syncthreads();

  short8 fa1[8];
#pragma unroll
  for (int kb = 0; kb < 8; kb++)
    fa1[kb] = *(const short8*)(qs_h2 + (size_t)kb * 512 + lane * 8);
  __syncthreads();

#pragma unroll
  for (int jj = 0; jj < 4; ++jj) {
    int jt = wv + jj * 8;
    f32x4 acc = (f32x4){0.f, 0.f, 0.f, 0.f};
#pragma unroll
    for (int kb = 0; kb < 8; kb++) {
      short8 fb = *(const short8*)(w1s + ((size_t)jt * 8 + kb) * 512 + lane * 8);
      acc = __builtin_amdgcn_mfma_f32_16x16x32_bf16(fa1[kb], fb, acc, 0, 0, 0);
    }
    int col = jt * 16 + r16;
    float bj = b1[col];
#pragma unroll
    for (int reg = 0; reg < 4; reg++) {
      int row_l = quad * 4 + reg;
      float v = fmaxf(acc[reg] + bj, 0.f);
      size_t o = (size_t)(col >> 5) * 512 +
                 (size_t)(((col >> 3) & 3) * 16 + row_l) * 8 + (col & 7);
      h1s[o] = bf16_rne(v);
    }
  }
  __syncthreads();

#pragma unroll
  for (int jj = 0; jj < 2; ++jj) {
    int jt = wv + jj * 8;
    f32x4 acc = (f32x4){0.f, 0.f, 0.f, 0.f};
#pragma unroll
    for (int kb = 0; kb < 16; kb++) {
      short8 fa = *(const short8*)(h1s + (size_t)kb * 512 + lane * 8);
      short8 fb = *(const short8*)(w2s + ((size_t)jt * 16 + kb) * 512 + lane * 8);
      acc = __builtin_amdgcn_mfma_f32_16x16x32_bf16(fa, fb, acc, 0, 0, 0);
    }
    int col = jt * 16 + r16;
    float bj = b2[col];
#pragma unroll
    for (int reg = 0; reg < 4; reg++) {
      int row_l = quad * 4 + reg;
      float v = fmaxf(acc[reg] + bj, 0.f);
      size_t o = (size_t)(col >> 5) * 512 +
                 (size_t)(((col >> 3) & 3) * 16 + row_l) * 8 + (col & 7);
      qs_h2[o] = bf16_rne(v);
    }
  }
  __syncthreads();

  if (tid < 384) {
    int t = tid / 24, c = (tid - t * 24) * 4;
    *(float4*)(gts + (size_t)t * 96 + c) =
        *(const float4*)(neigh + (size_t)(t0 + t) * 96 + c);
  }

  if (wv < 6) {
    int jt = wv;
    f32x4 acc = (f32x4){0.f, 0.f, 0.f, 0.f};
#pragma unroll
    for (int kb = 0; kb < 8; kb++) {
      short8 fa = *(const short8*)(qs_h2 + (size_t)kb * 512 + lane * 8);
      short8 fb = *(const short8*)(w3s + ((size_t)jt * 8 + kb) * 512 + lane * 8);
      acc = __builtin_amdgcn_mfma_f32_16x16x32_bf16(fa, fb, acc, 0, 0, 0);
    }
    int col = jt * 16 + r16;
    float bj = b3[col];
#pragma unroll
    for (int reg = 0; reg < 4; reg++) {
      int row_l = quad * 4 + reg;
      rec[(size_t)row_l * 96 + col] = acc[reg] + bj;
    }
  }
  __syncthreads();

  float local = 0.f;
  {
    int t = tid >> 5, i = tid & 31;
    float rx = rec[t * 96 + 3 * i], ry = rec[t * 96 + 3 * i + 1], rz = rec[t * 96 + 3 * i + 2];
    float gx = gts[t * 96 + 3 * i], gy = gts[t * 96 + 3 * i + 1], gz = gts[t * 96 + 3 * i + 2];
    float mA = FLT_MAX, mB = FLT_MAX;
#pragma unroll
    for (int j = 0; j < 32; j++) {
      float dx = rx - gts[t * 96 + 3 * j], dy = ry - gts[t * 96 + 3 * j + 1],
            dz = rz - gts[t * 96 + 3 * j + 2];
      float d = dx * dx + dy * dy + dz * dz;
      mA = fminf(mA, d);
      dx = rec[t * 96 + 3 * j] - gx; dy = rec[t * 96 + 3 * j + 1] - gy;
      dz = rec[t * 96 + 3 * j + 2] - gz;
      d = dx * dx + dy * dy + dz * dz;
      mB = fminf(mB, d);
    }
    local = mA + mB;
  }
#pragma unroll
  for (int off = 32; off; off >>= 1) local += __shfl_down(local, off, 64);
  if (lane == 0) wsum[wv] = local;
  __syncthreads();
  if (tid == 0) {
    float s = 0.f;
#pragma unroll
    for (int w = 0; w < 8; w++) s += wsum[w];
    atomicAdd(out, s * (1.0f / (float)(NTOK * KPTS)));
  }
}

extern "C" void kernel_launch(void* const* d_in, const int* in_sizes, int n_in,
                              void* d_out, int out_size, void* d_ws, size_t ws_size,
                              hipStream_t stream) {
  const float* pf    = (const float*)d_in[0];
  const float* neigh = (const float*)d_in[1];
  const float* cb    = (const float*)d_in[2];
  const float* w1    = (const float*)d_in[3];
  const float* b1    = (const float*)d_in[4];
  const float* w2    = (const float*)d_in[5];
  const float* b2    = (const float*)d_in[6];
  const float* w3    = (const float*)d_in[7];
  const float* b3    = (const float*)d_in[8];
  float* out = (float*)d_out;
  char* base = (char*)d_ws;

  u64*   pkeys = (u64*)base;                       // 8 slices x 8192 x 8 B = 512 KB
  float* cnorm = (float*)(base + 0x200000);        // 32 KB
  char*  pf1   = base + 0x210000;                  // 2 MB each
  char*  pf2   = base + 0x410000;
  char*  cb1   = base + 0x610000;
  char*  cb2   = base + 0x810000;
  ushort* cb_bf = (ushort*)(base + 0xA10000);      // 4 MB
  ushort* w1s   = (ushort*)(base + 0xE10000);      // 256 KB
  ushort* w2s   = (ushort*)(base + 0xE50000);      // 256 KB
  ushort* w3s   = (ushort*)(base + 0xE90000);      // 48 KB

  prep_k<<<1164, 256, 0, stream>>>(pf, cb, w1, w2, w3,
                                   (i32x4*)pf1, (i32x4*)pf2, (i32x4*)cb1,
                                   (i32x4*)cb2, cb_bf, w1s, w2s, w3s, cnorm, out);
  argmin_k<<<dim3(CG, 128), 256, 65536, stream>>>(pf1, pf2, cb1, cb2, cnorm, pkeys);
  mlp_fused_k<<<512, 512, 0, stream>>>(pkeys, cb_bf, w1s, b1, w2s, b2,
                                       w3s, b3, neigh, out);
}